// Round 7
// baseline (1694.672 us; speedup 1.0000x reference)
//
#include <hip/hip_runtime.h>

#define REP20(M) M(0) M(1) M(2) M(3) M(4) M(5) M(6) M(7) M(8) M(9) \
                 M(10) M(11) M(12) M(13) M(14) M(15) M(16) M(17) M(18) M(19)

__device__ __forceinline__ float rl(float x, int l) {
    return __int_as_float(__builtin_amdgcn_readlane(__float_as_int(x), l));
}
template <int C>
__device__ __forceinline__ float qperm(float x) {
    return __int_as_float(__builtin_amdgcn_mov_dpp(__float_as_int(x), C, 0xF, 0xF, false));
}
__device__ __forceinline__ float rcp_(float x) { return __builtin_amdgcn_rcpf(x); }
__device__ __forceinline__ float sigmf(float a) { return rcp_(1.0f + __expf(-a)); }
__device__ __forceinline__ float tanh_(float a) {
    return fmaf(2.0f, rcp_(1.0f + __expf(-2.0f * a)) - 1.0f, 1.0f);
}
// m=1 -> sigmoid, m=2 -> tanh
__device__ __forceinline__ float actf(float a, float m) {
    float r = rcp_(1.0f + __expf(-m * a));
    return fmaf(m, r - 1.0f, 1.0f);
}

// dot over SGPR-held h-state (sh0..sh19), two interleaved chains
#define DOTS(P, R) { \
    float zE = P##0 * sh0,  zO = P##1 * sh1; \
    zE = fmaf(P##2,  sh2,  zE); zO = fmaf(P##3,  sh3,  zO); \
    zE = fmaf(P##4,  sh4,  zE); zO = fmaf(P##5,  sh5,  zO); \
    zE = fmaf(P##6,  sh6,  zE); zO = fmaf(P##7,  sh7,  zO); \
    zE = fmaf(P##8,  sh8,  zE); zO = fmaf(P##9,  sh9,  zO); \
    zE = fmaf(P##10, sh10, zE); zO = fmaf(P##11, sh11, zO); \
    zE = fmaf(P##12, sh12, zE); zO = fmaf(P##13, sh13, zO); \
    zE = fmaf(P##14, sh14, zE); zO = fmaf(P##15, sh15, zO); \
    zE = fmaf(P##16, sh16, zE); zO = fmaf(P##17, sh17, zO); \
    zE = fmaf(P##18, sh18, zE); zO = fmaf(P##19, sh19, zO); \
    R += zE + zO; }

// dot over VGPR c-state (cc0..cc19), two interleaved chains
#define DOTC(P, R) { \
    float zE = P##0 * cc0,  zO = P##1 * cc1; \
    zE = fmaf(P##2,  cc2,  zE); zO = fmaf(P##3,  cc3,  zO); \
    zE = fmaf(P##4,  cc4,  zE); zO = fmaf(P##5,  cc5,  zO); \
    zE = fmaf(P##6,  cc6,  zE); zO = fmaf(P##7,  cc7,  zO); \
    zE = fmaf(P##8,  cc8,  zE); zO = fmaf(P##9,  cc9,  zO); \
    zE = fmaf(P##10, cc10, zE); zO = fmaf(P##11, cc11, zO); \
    zE = fmaf(P##12, cc12, zE); zO = fmaf(P##13, cc13, zO); \
    zE = fmaf(P##14, cc14, zE); zO = fmaf(P##15, cc15, zO); \
    zE = fmaf(P##16, cc16, zE); zO = fmaf(P##17, cc17, zO); \
    zE = fmaf(P##18, cc18, zE); zO = fmaf(P##19, cc19, zO); \
    R += zE + zO; }

#define LOADC(BASE) { \
    const float4* q_ = (const float4*)(BASE); \
    float4 A4 = q_[0], B4 = q_[1], C4 = q_[2], D4 = q_[3], E4 = q_[4]; \
    cc0 = A4.x; cc1 = A4.y; cc2  = A4.z; cc3  = A4.w; \
    cc4 = B4.x; cc5 = B4.y; cc6  = B4.z; cc7  = B4.w; \
    cc8 = C4.x; cc9 = C4.y; cc10 = C4.z; cc11 = C4.w; \
    cc12 = D4.x; cc13 = D4.y; cc14 = D4.z; cc15 = D4.w; \
    cc16 = E4.x; cc17 = E4.y; cc18 = E4.z; cc19 = E4.w; }

#define RLH(k) sh##k = rl(hn, 2 * (k));

// layer-2 combine from actL (gates i,f,g,o on lanes 40..43), updates c2my/h2my
#define L2COMBINE(DEST_IDX_EXPR)  { \
    float i2 = qperm<0x00>(actL), f2 = qperm<0x55>(actL); \
    float g2 = qperm<0xAA>(actL), o2 = qperm<0xFF>(actL); \
    float c2n = fmaf(f2, c2my, i2 * g2); \
    h2my = o2 * tanh_(c2n); \
    c2my = c2n; \
    if (lane == 40) op[DEST_IDX_EXPR] = c2n; }

__global__ __launch_bounds__(64, 1)
__attribute__((amdgpu_waves_per_eu(1, 1)))
void lstm2_kernel(const float* __restrict__ x_in,
                  const float* __restrict__ Wih1,
                  const float* __restrict__ Whh1,
                  const float* __restrict__ bih1,
                  const float* __restrict__ bhh1,
                  const float* __restrict__ Wih2,
                  const float* __restrict__ Whh2,
                  const float* __restrict__ bih2,
                  const float* __restrict__ bhh2,
                  float* __restrict__ out,
                  int T, int F)
{
    const int  lane = threadIdx.x;        // 1 wave = 1 batch chain
    const int  b    = blockIdx.x;
    const int  p    = lane & 1;
    int        j    = lane >> 1; if (j > 19) j = 19;
    const bool isL2 = (lane >= 40 && lane < 44);
    const int  g    = isL2 ? (lane - 40) : 0;

    // double-buffered c1 broadcast (only consumer: layer-2 dot, 1 step behind)
    __shared__ float sb[2][24];
    if (lane < 48) ((float*)sb)[lane] = 0.0f;
    __builtin_amdgcn_wave_barrier();

    // quad layout: lane 2j+0 -> rows (i_j, g_j); lane 2j+1 -> rows (f_j, o_j)
    const int rA = j + 20 * p;            // i / f
    const int rB = 40 + j + 20 * p;       // g / o

    const float* WArow = isL2 ? (Wih2 + g * 20) : (Whh1 + rA * 20);
    const float* WBrow = Whh1 + rB * 20;

    // launder: loads below are no longer provably-invariant -> cannot be
    // rematerialized inside the loop; values must stay register-resident.
    asm volatile("" : "+v"(WArow), "+v"(WBrow));

    const float4* wap = (const float4*)WArow;
    const float4* wbp = (const float4*)WBrow;
    float4 La0 = wap[0], La1 = wap[1], La2 = wap[2], La3 = wap[3], La4 = wap[4];
    float4 Lb0 = wbp[0], Lb1 = wbp[1], Lb2 = wbp[2], Lb3 = wbp[3], Lb4 = wbp[4];
    float wA0 = La0.x, wA1 = La0.y, wA2  = La0.z, wA3  = La0.w,
          wA4 = La1.x, wA5 = La1.y, wA6  = La1.z, wA7  = La1.w,
          wA8 = La2.x, wA9 = La2.y, wA10 = La2.z, wA11 = La2.w,
          wA12 = La3.x, wA13 = La3.y, wA14 = La3.z, wA15 = La3.w,
          wA16 = La4.x, wA17 = La4.y, wA18 = La4.z, wA19 = La4.w;
    float wB0 = Lb0.x, wB1 = Lb0.y, wB2  = Lb0.z, wB3  = Lb0.w,
          wB4 = Lb1.x, wB5 = Lb1.y, wB6  = Lb1.z, wB7  = Lb1.w,
          wB8 = Lb2.x, wB9 = Lb2.y, wB10 = Lb2.z, wB11 = Lb2.w,
          wB12 = Lb3.x, wB13 = Lb3.y, wB14 = Lb3.z, wB15 = Lb3.w,
          wB16 = Lb4.x, wB17 = Lb4.y, wB18 = Lb4.z, wB19 = Lb4.w;

    float wxA, wxB, bsA, bsB;
    {
        float u_wxA = Wih1[rA], u_wxB = Wih1[rB];
        float u_bsA = bih1[rA] + bhh1[rA];
        float u_bsB = bih1[rB] + bhh1[rB];
        float l_wxA = Whh2[g];            // multiplies h2 (O=1)
        float l_bsA = bih2[g] + bhh2[g];
        wxA = isL2 ? l_wxA : u_wxA;
        bsA = isL2 ? l_bsA : u_bsA;
        wxB = u_wxB;  bsB = u_bsB;
    }
    const float mB = p ? 1.0f : 2.0f;               // B row: g -> tanh, o -> sigm
    const float mL = (lane == 42) ? 2.0f : 1.0f;    // L2 'g' gate -> tanh

    // h-state in SGPRs (wave-uniform), c-state temporaries
#define DSH(k) float sh##k = 0.0f;
    REP20(DSH)
#undef DSH
    float cc0, cc1, cc2, cc3, cc4, cc5, cc6, cc7, cc8, cc9,
          cc10, cc11, cc12, cc13, cc14, cc15, cc16, cc17, cc18, cc19;

    float c1my = 0.0f, c2my = 0.0f, h2my = 0.0f;

    const float* xp = x_in + (long)b * T;
    float*       op = out  + (long)b * (T + F);

    float xr = xp[0];
    float x1 = xp[T > 1 ? 1 : 0];
    float x2 = xp[T > 2 ? 2 : 0];

    // ================= main scan: layer-2 runs 1 step behind =================
    for (int t = 0; t < T; ++t) {
        LOADC(sb[t & 1])                  // c1(t-1); latency hidden under layer-1
        int tn = t + 3; tn = (tn < T) ? tn : (T - 1);
        const float xf = xp[tn];

        // layer-1 gate dots over SGPR h-state  (L2 lanes: garbage, unused)
        float aA = fmaf(wxA, xr, bsA);
        float aB = fmaf(wxB, xr, bsB);
        DOTS(wA, aA)
        DOTS(wB, aB)
        // layer-2 gate dot over c1(t-1)       (main lanes: garbage, unused)
        float aL = fmaf(wxA, h2my, bsA);
        DOTC(wA, aL)

        float actA = sigmf(aA);           // i / f  (both sigmoid)
        float actB = actf(aB, mB);        // g(tanh) / o(sigm)
        float actL = actf(aL, mL);        // layer-2 own gate

        float nbA = qperm<0xB1>(actA);    // quad_perm [1,0,3,2]: partner's A
        float nbB = qperm<0xB1>(actB);
        float gi = p ? nbA : actA;
        float gf = p ? actA : nbA;
        float gg = p ? nbB : actB;
        float go = p ? actB : nbB;

        float cn = fmaf(gf, c1my, gi * gg);
        c1my = cn;
        if (!p && lane < 40) sb[(t & 1) ^ 1][j] = cn;   // publish c1(t) for L2
        float hn = go * tanh_(cn);

        REP20(RLH)                        // sh <- h1(t) via readlane (even lanes)

        if (t > 0) L2COMBINE(t - 1)       // layer-2 step t-1

        asm volatile("" ::: "memory");
        __builtin_amdgcn_wave_barrier();
        xr = x1; x1 = x2; x2 = xf;
    }

    // ================= drain: layer-2 step T-1 =================
    {
        LOADC(sb[T & 1])                  // c1(T-1)
        float aL = fmaf(wxA, h2my, bsA);
        DOTC(wA, aL)
        float actL = actf(aL, mL);
        L2COMBINE(T - 1)
    }
    float xF = rl(c2my, 40);

    // ================= future phase (F steps, serial) =================
    for (int i = 0; i < F; ++i) {
        float aA = fmaf(wxA, xF, bsA);
        float aB = fmaf(wxB, xF, bsB);
        DOTS(wA, aA)
        DOTS(wB, aB)
        float actA = sigmf(aA);
        float actB = actf(aB, mB);
        float nbA = qperm<0xB1>(actA);
        float nbB = qperm<0xB1>(actB);
        float gi = p ? nbA : actA;
        float gf = p ? actA : nbA;
        float gg = p ? nbB : actB;
        float go = p ? actB : nbB;
        float cn = fmaf(gf, c1my, gi * gg);
        c1my = cn;
        if (!p && lane < 40) sb[0][j] = cn;             // c1 of THIS step
        float hn = go * tanh_(cn);
        REP20(RLH)
        asm volatile("" ::: "memory");
        __builtin_amdgcn_wave_barrier();

        LOADC(sb[0])
        float aL = fmaf(wxA, h2my, bsA);
        DOTC(wA, aL)
        float actL = actf(aL, mL);
        L2COMBINE(T + i)
        xF = rl(c2my, 40);
        asm volatile("" ::: "memory");
        __builtin_amdgcn_wave_barrier();
    }
}

extern "C" void kernel_launch(void* const* d_in, const int* in_sizes, int n_in,
                              void* d_out, int out_size, void* d_ws, size_t ws_size,
                              hipStream_t stream) {
    const float* x    = (const float*)d_in[0];
    const float* Wih1 = (const float*)d_in[1];
    const float* Whh1 = (const float*)d_in[2];
    const float* bih1 = (const float*)d_in[3];
    const float* bhh1 = (const float*)d_in[4];
    const float* Wih2 = (const float*)d_in[5];
    const float* Whh2 = (const float*)d_in[6];
    const float* bih2 = (const float*)d_in[7];
    const float* bhh2 = (const float*)d_in[8];
    float* out = (float*)d_out;

    const int B = 1024;
    const int T = in_sizes[0] / B;        // 4096
    const int F = out_size / B - T;       // 16

    hipLaunchKernelGGL(lstm2_kernel, dim3(B), dim3(64), 0, stream,
                       x, Wih1, Whh1, bih1, bhh1, Wih2, Whh2, bih2, bhh2, out, T, F);
}

// Round 8
// 1674.191 us; speedup vs baseline: 1.0122x; 1.0122x over previous
//
#include <hip/hip_runtime.h>

#define REP20(M) M(0) M(1) M(2) M(3) M(4) M(5) M(6) M(7) M(8) M(9) \
                 M(10) M(11) M(12) M(13) M(14) M(15) M(16) M(17) M(18) M(19)

__device__ __forceinline__ float rl(float x, int l) {
    return __int_as_float(__builtin_amdgcn_readlane(__float_as_int(x), l));
}
template <int C>
__device__ __forceinline__ float qperm(float x) {
    return __int_as_float(__builtin_amdgcn_mov_dpp(__float_as_int(x), C, 0xF, 0xF, false));
}
__device__ __forceinline__ float rcp_(float x) { return __builtin_amdgcn_rcpf(x); }
__device__ __forceinline__ float sigmf(float a) { return rcp_(1.0f + __expf(-a)); }
__device__ __forceinline__ float tanh_(float a) {
    return fmaf(2.0f, rcp_(1.0f + __expf(-2.0f * a)) - 1.0f, 1.0f);
}
// m=1 -> sigmoid, m=2 -> tanh
__device__ __forceinline__ float actf(float a, float m) {
    float r = rcp_(1.0f + __expf(-m * a));
    return fmaf(m, r - 1.0f, 1.0f);
}

// define value via volatile asm: result is non-rematerializable, non-sinkable;
// with waves_per_eu(1,1) the RA has no pressure motive to spill it either.
#define DEFV(x) asm volatile("v_mov_b32 %0, %1" : "=v"(x) : "v"(x));

// dot over SGPR-held h-state (sh0..sh19), two interleaved chains
#define DOTS(P, R) { \
    float zE = P##0 * sh0,  zO = P##1 * sh1; \
    zE = fmaf(P##2,  sh2,  zE); zO = fmaf(P##3,  sh3,  zO); \
    zE = fmaf(P##4,  sh4,  zE); zO = fmaf(P##5,  sh5,  zO); \
    zE = fmaf(P##6,  sh6,  zE); zO = fmaf(P##7,  sh7,  zO); \
    zE = fmaf(P##8,  sh8,  zE); zO = fmaf(P##9,  sh9,  zO); \
    zE = fmaf(P##10, sh10, zE); zO = fmaf(P##11, sh11, zO); \
    zE = fmaf(P##12, sh12, zE); zO = fmaf(P##13, sh13, zO); \
    zE = fmaf(P##14, sh14, zE); zO = fmaf(P##15, sh15, zO); \
    zE = fmaf(P##16, sh16, zE); zO = fmaf(P##17, sh17, zO); \
    zE = fmaf(P##18, sh18, zE); zO = fmaf(P##19, sh19, zO); \
    R += zE + zO; }

// dot over VGPR c-state (cc0..cc19), two interleaved chains
#define DOTC(P, R) { \
    float zE = P##0 * cc0,  zO = P##1 * cc1; \
    zE = fmaf(P##2,  cc2,  zE); zO = fmaf(P##3,  cc3,  zO); \
    zE = fmaf(P##4,  cc4,  zE); zO = fmaf(P##5,  cc5,  zO); \
    zE = fmaf(P##6,  cc6,  zE); zO = fmaf(P##7,  cc7,  zO); \
    zE = fmaf(P##8,  cc8,  zE); zO = fmaf(P##9,  cc9,  zO); \
    zE = fmaf(P##10, cc10, zE); zO = fmaf(P##11, cc11, zO); \
    zE = fmaf(P##12, cc12, zE); zO = fmaf(P##13, cc13, zO); \
    zE = fmaf(P##14, cc14, zE); zO = fmaf(P##15, cc15, zO); \
    zE = fmaf(P##16, cc16, zE); zO = fmaf(P##17, cc17, zO); \
    zE = fmaf(P##18, cc18, zE); zO = fmaf(P##19, cc19, zO); \
    R += zE + zO; }

#define LOADC(BASE) { \
    const float4* q_ = (const float4*)(BASE); \
    float4 A4 = q_[0], B4 = q_[1], C4 = q_[2], D4 = q_[3], E4 = q_[4]; \
    cc0 = A4.x; cc1 = A4.y; cc2  = A4.z; cc3  = A4.w; \
    cc4 = B4.x; cc5 = B4.y; cc6  = B4.z; cc7  = B4.w; \
    cc8 = C4.x; cc9 = C4.y; cc10 = C4.z; cc11 = C4.w; \
    cc12 = D4.x; cc13 = D4.y; cc14 = D4.z; cc15 = D4.w; \
    cc16 = E4.x; cc17 = E4.y; cc18 = E4.z; cc19 = E4.w; }

#define RLH(k) sh##k = rl(hn, 2 * (k));

// layer-2 combine from actL (gates i,f,g,o on lanes 40..43), updates c2my/h2my
#define L2COMBINE(DEST_IDX_EXPR)  { \
    float i2 = qperm<0x00>(actL), f2 = qperm<0x55>(actL); \
    float g2 = qperm<0xAA>(actL), o2 = qperm<0xFF>(actL); \
    float c2n = fmaf(f2, c2my, i2 * g2); \
    h2my = o2 * tanh_(c2n); \
    c2my = c2n; \
    if (lane == 40) op[DEST_IDX_EXPR] = c2n; }

__global__ __launch_bounds__(64, 1)
__attribute__((amdgpu_waves_per_eu(1, 1)))
void lstm2_kernel(const float* __restrict__ x_in,
                  const float* __restrict__ Wih1,
                  const float* __restrict__ Whh1,
                  const float* __restrict__ bih1,
                  const float* __restrict__ bhh1,
                  const float* __restrict__ Wih2,
                  const float* __restrict__ Whh2,
                  const float* __restrict__ bih2,
                  const float* __restrict__ bhh2,
                  float* __restrict__ out,
                  int T, int F)
{
    const int  lane = threadIdx.x;        // 1 wave = 1 batch chain
    const int  b    = blockIdx.x;
    const int  p    = lane & 1;
    int        j    = lane >> 1; if (j > 19) j = 19;
    const bool isL2 = (lane >= 40 && lane < 44);
    const int  g    = isL2 ? (lane - 40) : 0;

    // double-buffered c1 broadcast (only consumer: layer-2 dot, 1 step behind)
    __shared__ float sb[2][24];
    if (lane < 48) ((float*)sb)[lane] = 0.0f;
    __builtin_amdgcn_wave_barrier();

    // quad layout: lane 2j+0 -> rows (i_j, g_j); lane 2j+1 -> rows (f_j, o_j)
    const int rA = j + 20 * p;            // i / f
    const int rB = 40 + j + 20 * p;       // g / o

    const float* WArow = isL2 ? (Wih2 + g * 20) : (Whh1 + rA * 20);
    const float* WBrow = Whh1 + rB * 20;

    const float4* wap = (const float4*)WArow;
    const float4* wbp = (const float4*)WBrow;
    float4 La0 = wap[0], La1 = wap[1], La2 = wap[2], La3 = wap[3], La4 = wap[4];
    float4 Lb0 = wbp[0], Lb1 = wbp[1], Lb2 = wbp[2], Lb3 = wbp[3], Lb4 = wbp[4];
    float wA0 = La0.x, wA1 = La0.y, wA2  = La0.z, wA3  = La0.w,
          wA4 = La1.x, wA5 = La1.y, wA6  = La1.z, wA7  = La1.w,
          wA8 = La2.x, wA9 = La2.y, wA10 = La2.z, wA11 = La2.w,
          wA12 = La3.x, wA13 = La3.y, wA14 = La3.z, wA15 = La3.w,
          wA16 = La4.x, wA17 = La4.y, wA18 = La4.z, wA19 = La4.w;
    float wB0 = Lb0.x, wB1 = Lb0.y, wB2  = Lb0.z, wB3  = Lb0.w,
          wB4 = Lb1.x, wB5 = Lb1.y, wB6  = Lb1.z, wB7  = Lb1.w,
          wB8 = Lb2.x, wB9 = Lb2.y, wB10 = Lb2.z, wB11 = Lb2.w,
          wB12 = Lb3.x, wB13 = Lb3.y, wB14 = Lb3.z, wB15 = Lb3.w,
          wB16 = Lb4.x, wB17 = Lb4.y, wB18 = Lb4.z, wB19 = Lb4.w;

    float wxA, wxB, bsA, bsB;
    {
        float u_wxA = Wih1[rA], u_wxB = Wih1[rB];
        float u_bsA = bih1[rA] + bhh1[rA];
        float u_bsB = bih1[rB] + bhh1[rB];
        float l_wxA = Whh2[g];            // multiplies h2 (O=1)
        float l_bsA = bih2[g] + bhh2[g];
        wxA = isL2 ? l_wxA : u_wxA;
        bsA = isL2 ? l_bsA : u_bsA;
        wxB = u_wxB;  bsB = u_bsB;
    }

    // ---- anti-remat: every loop-invariant weight becomes a volatile-asm-defined
    // value; it can only live in a VGPR (or scratch, which waves_per_eu(1,1)
    // removes the motive for). ----
    DEFV(wA0) DEFV(wA1) DEFV(wA2)  DEFV(wA3)  DEFV(wA4)  DEFV(wA5)  DEFV(wA6)  DEFV(wA7)
    DEFV(wA8) DEFV(wA9) DEFV(wA10) DEFV(wA11) DEFV(wA12) DEFV(wA13) DEFV(wA14) DEFV(wA15)
    DEFV(wA16) DEFV(wA17) DEFV(wA18) DEFV(wA19)
    DEFV(wB0) DEFV(wB1) DEFV(wB2)  DEFV(wB3)  DEFV(wB4)  DEFV(wB5)  DEFV(wB6)  DEFV(wB7)
    DEFV(wB8) DEFV(wB9) DEFV(wB10) DEFV(wB11) DEFV(wB12) DEFV(wB13) DEFV(wB14) DEFV(wB15)
    DEFV(wB16) DEFV(wB17) DEFV(wB18) DEFV(wB19)
    DEFV(wxA) DEFV(wxB) DEFV(bsA) DEFV(bsB)

    const float mB = p ? 1.0f : 2.0f;               // B row: g -> tanh, o -> sigm
    const float mL = (lane == 42) ? 2.0f : 1.0f;    // L2 'g' gate -> tanh

    // h-state in SGPRs (wave-uniform), c-state temporaries
#define DSH(k) float sh##k = 0.0f;
    REP20(DSH)
#undef DSH
    float cc0, cc1, cc2, cc3, cc4, cc5, cc6, cc7, cc8, cc9,
          cc10, cc11, cc12, cc13, cc14, cc15, cc16, cc17, cc18, cc19;

    float c1my = 0.0f, c2my = 0.0f, h2my = 0.0f;

    const float* xp = x_in + (long)b * T;
    float*       op = out  + (long)b * (T + F);

    float xr = xp[0];
    float x1 = xp[T > 1 ? 1 : 0];
    float x2 = xp[T > 2 ? 2 : 0];

    // ================= main scan: layer-2 runs 1 step behind =================
    for (int t = 0; t < T; ++t) {
        LOADC(sb[t & 1])                  // c1(t-1); latency hidden under layer-1
        int tn = t + 3; tn = (tn < T) ? tn : (T - 1);
        const float xf = xp[tn];

        // layer-1 gate dots over SGPR h-state  (L2 lanes: garbage, unused)
        float aA = fmaf(wxA, xr, bsA);
        float aB = fmaf(wxB, xr, bsB);
        DOTS(wA, aA)
        DOTS(wB, aB)
        // layer-2 gate dot over c1(t-1)       (main lanes: garbage, unused)
        float aL = fmaf(wxA, h2my, bsA);
        DOTC(wA, aL)

        float actA = sigmf(aA);           // i / f  (both sigmoid)
        float actB = actf(aB, mB);        // g(tanh) / o(sigm)
        float actL = actf(aL, mL);        // layer-2 own gate

        float nbA = qperm<0xB1>(actA);    // quad_perm [1,0,3,2]: partner's A
        float nbB = qperm<0xB1>(actB);
        float gi = p ? nbA : actA;
        float gf = p ? actA : nbA;
        float gg = p ? nbB : actB;
        float go = p ? actB : nbB;

        float cn = fmaf(gf, c1my, gi * gg);
        c1my = cn;
        if (!p && lane < 40) sb[(t & 1) ^ 1][j] = cn;   // publish c1(t) for L2
        float hn = go * tanh_(cn);

        REP20(RLH)                        // sh <- h1(t) via readlane (even lanes)

        if (t > 0) L2COMBINE(t - 1)       // layer-2 step t-1

        asm volatile("" ::: "memory");
        __builtin_amdgcn_wave_barrier();
        xr = x1; x1 = x2; x2 = xf;
    }

    // ================= drain: layer-2 step T-1 =================
    {
        LOADC(sb[T & 1])                  // c1(T-1)
        float aL = fmaf(wxA, h2my, bsA);
        DOTC(wA, aL)
        float actL = actf(aL, mL);
        L2COMBINE(T - 1)
    }
    float xF = rl(c2my, 40);

    // ================= future phase (F steps, serial) =================
    for (int i = 0; i < F; ++i) {
        float aA = fmaf(wxA, xF, bsA);
        float aB = fmaf(wxB, xF, bsB);
        DOTS(wA, aA)
        DOTS(wB, aB)
        float actA = sigmf(aA);
        float actB = actf(aB, mB);
        float nbA = qperm<0xB1>(actA);
        float nbB = qperm<0xB1>(actB);
        float gi = p ? nbA : actA;
        float gf = p ? actA : nbA;
        float gg = p ? nbB : actB;
        float go = p ? actB : nbB;
        float cn = fmaf(gf, c1my, gi * gg);
        c1my = cn;
        if (!p && lane < 40) sb[0][j] = cn;             // c1 of THIS step
        float hn = go * tanh_(cn);
        REP20(RLH)
        asm volatile("" ::: "memory");
        __builtin_amdgcn_wave_barrier();

        LOADC(sb[0])
        float aL = fmaf(wxA, h2my, bsA);
        DOTC(wA, aL)
        float actL = actf(aL, mL);
        L2COMBINE(T + i)
        xF = rl(c2my, 40);
        asm volatile("" ::: "memory");
        __builtin_amdgcn_wave_barrier();
    }
}

extern "C" void kernel_launch(void* const* d_in, const int* in_sizes, int n_in,
                              void* d_out, int out_size, void* d_ws, size_t ws_size,
                              hipStream_t stream) {
    const float* x    = (const float*)d_in[0];
    const float* Wih1 = (const float*)d_in[1];
    const float* Whh1 = (const float*)d_in[2];
    const float* bih1 = (const float*)d_in[3];
    const float* bhh1 = (const float*)d_in[4];
    const float* Wih2 = (const float*)d_in[5];
    const float* Whh2 = (const float*)d_in[6];
    const float* bih2 = (const float*)d_in[7];
    const float* bhh2 = (const float*)d_in[8];
    float* out = (float*)d_out;

    const int B = 1024;
    const int T = in_sizes[0] / B;        // 4096
    const int F = out_size / B - T;       // 16

    hipLaunchKernelGGL(lstm2_kernel, dim3(B), dim3(64), 0, stream,
                       x, Wih1, Whh1, bih1, bhh1, Wih2, Whh2, bih2, bhh2, out, T, F);
}

// Round 9
// 1225.462 us; speedup vs baseline: 1.3829x; 1.3662x over previous
//
#include <hip/hip_runtime.h>

typedef float v2f __attribute__((ext_vector_type(2)));

template <int C>
__device__ __forceinline__ float qperm(float x) {
    return __int_as_float(__builtin_amdgcn_mov_dpp(__float_as_int(x), C, 0xF, 0xF, false));
}
__device__ __forceinline__ float rl(float x, int l) {
    return __int_as_float(__builtin_amdgcn_readlane(__float_as_int(x), l));
}
__device__ __forceinline__ float rcp_(float x) { return __builtin_amdgcn_rcpf(x); }
__device__ __forceinline__ float ex2(float x)  { return __builtin_amdgcn_exp2f(x); }

// a is PRE-SCALED by m*log2e at weight-load time. m=1 -> sigmoid, m=2 -> tanh.
__device__ __forceinline__ float act2(float a, float m) {
    float r = rcp_(1.0f + ex2(-a));          // exp negation folds into v_exp modifier
    return fmaf(m, r - 1.0f, 1.0f);          // m=1: r ; m=2: 2r-1
}
__device__ __forceinline__ float tanh2(float x) {
    return fmaf(2.0f, rcp_(1.0f + ex2(-2.885390082f * x)) - 1.0f, 1.0f);
}

#define FMA2(a, b, c) __builtin_elementwise_fma(a, b, c)

// R += dot over 10 v2f pairs (packed fp32 FMA); state s0..s9 in scope
#define DOTP(P, R) { \
    v2f z0 = P##0 * s0; v2f z1 = P##1 * s1; \
    z0 = FMA2(P##2, s2, z0); z1 = FMA2(P##3, s3, z1); \
    z0 = FMA2(P##4, s4, z0); z1 = FMA2(P##5, s5, z1); \
    z0 = FMA2(P##6, s6, z0); z1 = FMA2(P##7, s7, z1); \
    z0 = FMA2(P##8, s8, z0); z1 = FMA2(P##9, s9, z1); \
    z0 = z0 + z1; R += z0.x + z0.y; }

// declare s0..s9 from 5 float4 LDS reads at float4-aligned BASE
#define LOADQ(BASE) \
    float4 A4 = (BASE)[0], B4 = (BASE)[1], C4 = (BASE)[2], D4 = (BASE)[3], E4 = (BASE)[4]; \
    v2f s0 = {A4.x, A4.y}, s1 = {A4.z, A4.w}, s2 = {B4.x, B4.y}, s3 = {B4.z, B4.w}, \
        s4 = {C4.x, C4.y}, s5 = {C4.z, C4.w}, s6 = {D4.x, D4.y}, s7 = {D4.z, D4.w}, \
        s8 = {E4.x, E4.y}, s9 = {E4.z, E4.w};

// layer-2 combine from actL (gates i,f,g,o on lanes 40..43)
#define L2COMBINE(DEST_IDX_EXPR) { \
    float i2 = qperm<0x00>(actL), f2 = qperm<0x55>(actL); \
    float g2 = qperm<0xAA>(actL), o2 = qperm<0xFF>(actL); \
    float c2n = fmaf(f2, c2my, i2 * g2); \
    h2my = o2 * tanh2(c2n); \
    c2my = c2n; \
    if (lane == 40) op[DEST_IDX_EXPR] = c2n; }

__global__ __launch_bounds__(64, 1)
void lstm2_kernel(const float* __restrict__ x_in,
                  const float* __restrict__ Wih1,
                  const float* __restrict__ Whh1,
                  const float* __restrict__ bih1,
                  const float* __restrict__ bhh1,
                  const float* __restrict__ Wih2,
                  const float* __restrict__ Whh2,
                  const float* __restrict__ bih2,
                  const float* __restrict__ bhh2,
                  float* __restrict__ out,
                  int T, int F)
{
    const int  lane = threadIdx.x;        // 1 wave = 1 batch chain
    const int  b    = blockIdx.x;
    const int  p    = lane & 1;
    int        j    = lane >> 1; if (j > 19) j = 19;   // idle lanes clamp
    const bool isL2 = (lane >= 40 && lane < 44);
    const int  g    = isL2 ? (lane - 40) : 0;

    // [ h1: 0..19 | c1: 24..43 ]; single buffer (per-wave DS ops are in-order)
    __shared__ float sb[48];
    if (lane < 48) sb[lane] = 0.0f;
    __builtin_amdgcn_wave_barrier();

    // quad layout: lane 2j+0 -> rows (i_j, g_j); lane 2j+1 -> rows (f_j, o_j)
    const int rA = j + 20 * p;            // i / f
    const int rB = 40 + j + 20 * p;       // g / o

    const float* WArow = isL2 ? (Wih2 + g * 20) : (Whh1 + rA * 20);
    const float* WBrow = Whh1 + rB * 20;

    const float4* wap = (const float4*)WArow;
    const float4* wbp = (const float4*)WBrow;
    float4 La0 = wap[0], La1 = wap[1], La2 = wap[2], La3 = wap[3], La4 = wap[4];
    float4 Lb0 = wbp[0], Lb1 = wbp[1], Lb2 = wbp[2], Lb3 = wbp[3], Lb4 = wbp[4];
    v2f wa0 = {La0.x,La0.y}, wa1 = {La0.z,La0.w}, wa2 = {La1.x,La1.y}, wa3 = {La1.z,La1.w},
        wa4 = {La2.x,La2.y}, wa5 = {La2.z,La2.w}, wa6 = {La3.x,La3.y}, wa7 = {La3.z,La3.w},
        wa8 = {La4.x,La4.y}, wa9 = {La4.z,La4.w};
    v2f wb0 = {Lb0.x,Lb0.y}, wb1 = {Lb0.z,Lb0.w}, wb2 = {Lb1.x,Lb1.y}, wb3 = {Lb1.z,Lb1.w},
        wb4 = {Lb2.x,Lb2.y}, wb5 = {Lb2.z,Lb2.w}, wb6 = {Lb3.x,Lb3.y}, wb7 = {Lb3.z,Lb3.w},
        wb8 = {Lb4.x,Lb4.y}, wb9 = {Lb4.z,Lb4.w};

    float wxA, wxB, bsA, bsB;
    {
        float u_wxA = Wih1[rA], u_wxB = Wih1[rB];
        float u_bsA = bih1[rA] + bhh1[rA];
        float u_bsB = bih1[rB] + bhh1[rB];
        float l_wxA = Whh2[g];            // multiplies h2 (O=1)
        float l_bsA = bih2[g] + bhh2[g];
        wxA = isL2 ? l_wxA : u_wxA;
        bsA = isL2 ? l_bsA : u_bsA;
        wxB = u_wxB;  bsB = u_bsB;
    }

    const float mB = p ? 1.0f : 2.0f;               // B row: g -> tanh, o -> sigm
    const float mL = (lane == 42) ? 2.0f : 1.0f;    // L2 'g' gate -> tanh
    const float mA = isL2 ? mL : 1.0f;              // A rows i/f -> sigm

    // fold m*log2e into weights/biases so activations use raw v_exp_f32
    const float LOG2E = 1.4426950408889634f;
    const float kA = LOG2E * mA;
    const float kB = LOG2E * mB;
    {
        v2f kA2 = {kA, kA}, kB2 = {kB, kB};
        wa0 *= kA2; wa1 *= kA2; wa2 *= kA2; wa3 *= kA2; wa4 *= kA2;
        wa5 *= kA2; wa6 *= kA2; wa7 *= kA2; wa8 *= kA2; wa9 *= kA2;
        wb0 *= kB2; wb1 *= kB2; wb2 *= kB2; wb3 *= kB2; wb4 *= kB2;
        wb5 *= kB2; wb6 *= kB2; wb7 *= kB2; wb8 *= kB2; wb9 *= kB2;
        wxA *= kA; bsA *= kA; wxB *= kB; bsB *= kB;
    }

    const float4* sp  = (const float4*)(sb + (isL2 ? 24 : 0));   // h | c view
    const float4* spc = (const float4*)(sb + 24);
    const float4* sph = (const float4*)sb;

    float c1my = 0.0f, c2my = 0.0f, h2my = 0.0f;

    const float* xp = x_in + (long)b * T;
    float*       op = out  + (long)b * (T + F);

    float xr = xp[0];
    float x1 = xp[T > 1 ? 1 : 0];
    float x2 = xp[T > 2 ? 2 : 0];

    // ================= main scan: layer-2 runs 1 step behind =================
    for (int t = 0; t < T; ++t) {
        LOADQ(sp)                         // h1(t-1) for main lanes | c1(t-1) for L2
        int tn = t + 3; tn = (tn < T) ? tn : (T - 1);
        const float xf = xp[tn];

        const float xinA = isL2 ? h2my : xr;
        float aA = fmaf(wxA, xinA, bsA);
        float aB = fmaf(wxB, xr,   bsB);
        DOTP(wa, aA)
        DOTP(wb, aB)

        float actA = act2(aA, mA);        // i / f  (L2 lanes: their own gate)
        float actB = act2(aB, mB);        // g(tanh) / o(sigm)

        float nbA = qperm<0xB1>(actA);    // quad_perm [1,0,3,2]: pair partner
        float nbB = qperm<0xB1>(actB);
        float gi = p ? nbA : actA;
        float gf = p ? actA : nbA;
        float gg = p ? nbB : actB;
        float go = p ? actB : nbB;

        float cn = fmaf(gf, c1my, gi * gg);
        c1my = cn;
        float hn = go * tanh2(cn);
        if (!p && lane < 40) { sb[24 + j] = cn; sb[j] = hn; }

        float actL = actA;                // lanes 40..43 hold layer-2 gates(t-1)
        if (t > 0) L2COMBINE(t - 1)

        asm volatile("" ::: "memory");
        __builtin_amdgcn_wave_barrier();
        xr = x1; x1 = x2; x2 = xf;
    }

    // ================= drain: layer-2 step T-1 =================
    {
        LOADQ(spc)                        // c1(T-1)
        float aL = fmaf(wxA, h2my, bsA);
        DOTP(wa, aL)
        float actL = act2(aL, mA);
        L2COMBINE(T - 1)
    }
    float xF = rl(c2my, 40);

    // ================= future phase (F steps, serial) =================
    for (int i = 0; i < F; ++i) {
        {   // layer 1 over h1(prev), input xF
            LOADQ(sph)
            float aA = fmaf(wxA, xF, bsA);
            float aB = fmaf(wxB, xF, bsB);
            DOTP(wa, aA)
            DOTP(wb, aB)
            float actA = act2(aA, mA);
            float actB = act2(aB, mB);
            float nbA = qperm<0xB1>(actA);
            float nbB = qperm<0xB1>(actB);
            float gi = p ? nbA : actA;
            float gf = p ? actA : nbA;
            float gg = p ? nbB : actB;
            float go = p ? actB : nbB;
            float cn = fmaf(gf, c1my, gi * gg);
            c1my = cn;
            float hn = go * tanh2(cn);
            if (!p && lane < 40) { sb[24 + j] = cn; sb[j] = hn; }
        }
        asm volatile("" ::: "memory");
        __builtin_amdgcn_wave_barrier();
        {   // layer 2 over c1 of THIS step
            LOADQ(spc)
            float aL = fmaf(wxA, h2my, bsA);
            DOTP(wa, aL)
            float actL = act2(aL, mA);
            L2COMBINE(T + i)
        }
        xF = rl(c2my, 40);
        asm volatile("" ::: "memory");
        __builtin_amdgcn_wave_barrier();
    }
}

extern "C" void kernel_launch(void* const* d_in, const int* in_sizes, int n_in,
                              void* d_out, int out_size, void* d_ws, size_t ws_size,
                              hipStream_t stream) {
    const float* x    = (const float*)d_in[0];
    const float* Wih1 = (const float*)d_in[1];
    const float* Whh1 = (const float*)d_in[2];
    const float* bih1 = (const float*)d_in[3];
    const float* bhh1 = (const float*)d_in[4];
    const float* Wih2 = (const float*)d_in[5];
    const float* Whh2 = (const float*)d_in[6];
    const float* bih2 = (const float*)d_in[7];
    const float* bhh2 = (const float*)d_in[8];
    float* out = (float*)d_out;

    const int B = 1024;
    const int T = in_sizes[0] / B;        // 4096
    const int F = out_size / B - T;       // 16

    hipLaunchKernelGGL(lstm2_kernel, dim3(B), dim3(64), 0, stream,
                       x, Wih1, Whh1, bih1, bhh1, Wih2, Whh2, bih2, bhh2, out, T, F);
}

// Round 10
// 987.787 us; speedup vs baseline: 1.7156x; 1.2406x over previous
//
#include <hip/hip_runtime.h>

typedef float v2f __attribute__((ext_vector_type(2)));

template <int C>
__device__ __forceinline__ float qperm(float x) {
    return __int_as_float(__builtin_amdgcn_mov_dpp(__float_as_int(x), C, 0xF, 0xF, false));
}
__device__ __forceinline__ float rl(float x, int l) {
    return __int_as_float(__builtin_amdgcn_readlane(__float_as_int(x), l));
}
__device__ __forceinline__ float rcp_(float x) { return __builtin_amdgcn_rcpf(x); }
__device__ __forceinline__ float ex2(float x)  { return __builtin_amdgcn_exp2f(x); }

#define FMA2(a, b, c) __builtin_elementwise_fma(a, b, c)
#define NTANH_K 2.885390082f   /* 2*log2(e) */

// R += dot over 10 v2f pairs; 4 chains, depth ~6
#define DOTP(P, R) { \
    v2f z0 = P##0 * s0, z1 = P##1 * s1, z2 = P##2 * s2, z3 = P##3 * s3; \
    z0 = FMA2(P##4, s4, z0); z1 = FMA2(P##5, s5, z1); \
    z2 = FMA2(P##6, s6, z2); z3 = FMA2(P##7, s7, z3); \
    z0 = FMA2(P##8, s8, z0); z1 = FMA2(P##9, s9, z1); \
    z0 = z0 + z1; z2 = z2 + z3; z0 = z0 + z2; \
    R += z0.x + z0.y; }

// declare s0..s9 from 5 float4 LDS reads at float4-aligned BASE
#define LOADQ(BASE) \
    float4 A4 = (BASE)[0], B4 = (BASE)[1], C4 = (BASE)[2], D4 = (BASE)[3], E4 = (BASE)[4]; \
    v2f s0 = {A4.x, A4.y}, s1 = {A4.z, A4.w}, s2 = {B4.x, B4.y}, s3 = {B4.z, B4.w}, \
        s4 = {C4.x, C4.y}, s5 = {C4.z, C4.w}, s6 = {D4.x, D4.y}, s7 = {D4.z, D4.w}, \
        s8 = {E4.x, E4.y}, s9 = {E4.z, E4.w};

// layer-2 combine from carried actL (gates on lanes 40..43); RB <- c2n
#define L2C(RB) { \
    float i2 = qperm<0x00>(actL), f2 = qperm<0x55>(actL); \
    float g2 = qperm<0xAA>(actL), o2 = qperm<0xFF>(actL); \
    float c2n = fmaf(f2, c2my, i2 * g2); \
    float rt2 = rcp_(1.0f + ex2(-NTANH_K * c2n)); \
    h2my = fmaf(o2 + o2, rt2, -o2); \
    c2my = c2n; \
    RB = c2n; }

// one scan step; POS in [0,3] static; L2 block passed as __VA_ARGS__
#define STEP(TT, POS, XUSE, XFVAR, ...) { \
    LOADQ(sp) \
    int tn_ = (TT) + (POS) + 3; tn_ = tn_ < T ? tn_ : T - 1; \
    XFVAR = xp[tn_]; \
    __VA_ARGS__ \
    const float xinA = isL2 ? h2my : (XUSE); \
    float aA = fmaf(wxA, xinA, bsA); \
    float aB = fmaf(wxB, (XUSE), bsB); \
    DOTP(wa, aA) \
    DOTP(wb, aB) \
    float rA_ = rcp_(1.0f + ex2(-aA)); \
    float rB_ = rcp_(1.0f + ex2(-aB)); \
    float actA = fmaf(mA, rA_, onemA); \
    float actB = fmaf(mB, rB_, onemB); \
    float nbA = qperm<0xB1>(actA); \
    float nbB = qperm<0xB1>(actB); \
    float gi = p ? nbA : actA; \
    float gf = p ? actA : nbA; \
    float gg = p ? nbB : actB; \
    float go = p ? actB : nbB; \
    float cn = fmaf(gf, c1my, gi * gg); \
    c1my = cn; \
    float rT_ = rcp_(1.0f + ex2(-NTANH_K * cn)); \
    float hn = fmaf(go + go, rT_, -go); \
    if (!p && lane < 40) { sb[24 + j] = cn; sb[j] = hn; } \
    actL = actA; \
    asm volatile("" ::: "memory"); \
}

__global__ __launch_bounds__(64, 1)
void lstm2_kernel(const float* __restrict__ x_in,
                  const float* __restrict__ Wih1,
                  const float* __restrict__ Whh1,
                  const float* __restrict__ bih1,
                  const float* __restrict__ bhh1,
                  const float* __restrict__ Wih2,
                  const float* __restrict__ Whh2,
                  const float* __restrict__ bih2,
                  const float* __restrict__ bhh2,
                  float* __restrict__ out,
                  int T, int F)
{
    const int  lane = threadIdx.x;        // 1 wave = 1 batch chain
    const int  b    = blockIdx.x;
    const int  p    = lane & 1;
    int        j    = lane >> 1; if (j > 19) j = 19;   // idle lanes clamp
    const bool isL2 = (lane >= 40 && lane < 44);
    const int  g    = isL2 ? (lane - 40) : 0;

    // [ h1: 0..19 | c1: 24..43 ]
    __shared__ float sb[48];
    if (lane < 48) sb[lane] = 0.0f;
    __builtin_amdgcn_wave_barrier();
    asm volatile("" ::: "memory");

    // quad layout: lane 2j+0 -> rows (i_j, g_j); lane 2j+1 -> rows (f_j, o_j)
    const int rA = j + 20 * p;            // i / f
    const int rB = 40 + j + 20 * p;       // g / o

    const float* WArow = isL2 ? (Wih2 + g * 20) : (Whh1 + rA * 20);
    const float* WBrow = Whh1 + rB * 20;

    const float4* wap = (const float4*)WArow;
    const float4* wbp = (const float4*)WBrow;
    float4 La0 = wap[0], La1 = wap[1], La2 = wap[2], La3 = wap[3], La4 = wap[4];
    float4 Lb0 = wbp[0], Lb1 = wbp[1], Lb2 = wbp[2], Lb3 = wbp[3], Lb4 = wbp[4];
    v2f wa0 = {La0.x,La0.y}, wa1 = {La0.z,La0.w}, wa2 = {La1.x,La1.y}, wa3 = {La1.z,La1.w},
        wa4 = {La2.x,La2.y}, wa5 = {La2.z,La2.w}, wa6 = {La3.x,La3.y}, wa7 = {La3.z,La3.w},
        wa8 = {La4.x,La4.y}, wa9 = {La4.z,La4.w};
    v2f wb0 = {Lb0.x,Lb0.y}, wb1 = {Lb0.z,Lb0.w}, wb2 = {Lb1.x,Lb1.y}, wb3 = {Lb1.z,Lb1.w},
        wb4 = {Lb2.x,Lb2.y}, wb5 = {Lb2.z,Lb2.w}, wb6 = {Lb3.x,Lb3.y}, wb7 = {Lb3.z,Lb3.w},
        wb8 = {Lb4.x,Lb4.y}, wb9 = {Lb4.z,Lb4.w};

    float wxA, wxB, bsA, bsB;
    {
        float u_wxA = Wih1[rA], u_wxB = Wih1[rB];
        float u_bsA = bih1[rA] + bhh1[rA];
        float u_bsB = bih1[rB] + bhh1[rB];
        float l_wxA = Whh2[g];            // multiplies h2 (O=1)
        float l_bsA = bih2[g] + bhh2[g];
        wxA = isL2 ? l_wxA : u_wxA;
        bsA = isL2 ? l_bsA : u_bsA;
        wxB = u_wxB;  bsB = u_bsB;
    }

    const float mB = p ? 1.0f : 2.0f;               // B row: g -> tanh, o -> sigm
    const float mL = (lane == 42) ? 2.0f : 1.0f;    // L2 'g' gate -> tanh
    const float mA = isL2 ? mL : 1.0f;              // A rows i/f -> sigm
    const float onemA = 1.0f - mA, onemB = 1.0f - mB;

    // fold m*log2e into weights/biases so activations use raw v_exp_f32
    const float LOG2E = 1.4426950408889634f;
    const float kA = LOG2E * mA;
    const float kB = LOG2E * mB;
    {
        v2f kA2 = {kA, kA}, kB2 = {kB, kB};
        wa0 *= kA2; wa1 *= kA2; wa2 *= kA2; wa3 *= kA2; wa4 *= kA2;
        wa5 *= kA2; wa6 *= kA2; wa7 *= kA2; wa8 *= kA2; wa9 *= kA2;
        wb0 *= kB2; wb1 *= kB2; wb2 *= kB2; wb3 *= kB2; wb4 *= kB2;
        wb5 *= kB2; wb6 *= kB2; wb7 *= kB2; wb8 *= kB2; wb9 *= kB2;
        wxA *= kA; bsA *= kA; wxB *= kB; bsB *= kB;
    }

    const float4* sp  = (const float4*)(sb + (isL2 ? 24 : 0));   // h | c view
    const float4* spc = (const float4*)(sb + 24);
    const float4* sph = (const float4*)sb;

    float c1my = 0.0f, c2my = 0.0f, h2my = 0.0f;
    float actL = 0.0f;
    float rb0 = 0.0f, rb1 = 0.0f, rb2 = 0.0f, rb3 = 0.0f;

    const float* xp = x_in + (long)b * T;
    float*       op = out  + (long)b * (T + F);

    float xA = xp[0];
    float xB = xp[T > 1 ? 1 : 0];
    float xC = xp[T > 2 ? 2 : 0];

    // ============ main scan, unrolled x4; layer-2 combine one step behind,
    // ============ placed in the ds_read shadow; out-stores batched x4 ============
    for (int t = 0; t < T; t += 4) {
        float nx0, nx1, nx2, nx3;
        STEP(t, 0, xA, nx0, if (t > 0) { L2C(rb2) })
        STEP(t, 1, xB, nx1, if (t > 0) { L2C(rb3)
            if (lane == 40) { float4 v4; v4.x = rb0; v4.y = rb1; v4.z = rb2; v4.w = rb3;
                              *(float4*)(op + t - 4) = v4; } })
        STEP(t, 2, xC, nx2, L2C(rb0))
        STEP(t, 3, nx0, nx3, L2C(rb1))
        xA = nx1; xB = nx2; xC = nx3;
    }

    // ============ drain: combine s=T-2, compute+combine s=T-1, store last 4 ============
    L2C(rb2)                              // s = T-2 (actL = gates(T-2))
    {
        LOADQ(spc)                        // c1(T-1)
        float aL = fmaf(wxA, h2my, bsA);
        DOTP(wa, aL)
        float rL_ = rcp_(1.0f + ex2(-aL));
        actL = fmaf(mA, rL_, onemA);
    }
    L2C(rb3)                              // s = T-1
    if (lane == 40) { float4 v4; v4.x = rb0; v4.y = rb1; v4.z = rb2; v4.w = rb3;
                      *(float4*)(op + T - 4) = v4; }
    float xF = rl(c2my, 40);

    // ============ future phase (F steps, serial) ============
    for (int i = 0; i < F; ++i) {
        {   // layer 1 over h1(prev), input xF
            LOADQ(sph)
            float aA = fmaf(wxA, xF, bsA);
            float aB = fmaf(wxB, xF, bsB);
            DOTP(wa, aA)
            DOTP(wb, aB)
            float rA_ = rcp_(1.0f + ex2(-aA));
            float rB_ = rcp_(1.0f + ex2(-aB));
            float actA = fmaf(mA, rA_, onemA);
            float actB = fmaf(mB, rB_, onemB);
            float nbA = qperm<0xB1>(actA);
            float nbB = qperm<0xB1>(actB);
            float gi = p ? nbA : actA;
            float gf = p ? actA : nbA;
            float gg = p ? nbB : actB;
            float go = p ? actB : nbB;
            float cn = fmaf(gf, c1my, gi * gg);
            c1my = cn;
            float rT_ = rcp_(1.0f + ex2(-NTANH_K * cn));
            float hn = fmaf(go + go, rT_, -go);
            if (!p && lane < 40) { sb[24 + j] = cn; sb[j] = hn; }
        }
        asm volatile("" ::: "memory");
        __builtin_amdgcn_wave_barrier();
        {   // layer 2 over c1 of THIS step
            LOADQ(spc)
            float aL = fmaf(wxA, h2my, bsA);
            DOTP(wa, aL)
            float rL_ = rcp_(1.0f + ex2(-aL));
            actL = fmaf(mA, rL_, onemA);
            float dummy;
            L2C(dummy)
            if (lane == 40) op[T + i] = dummy;
        }
        xF = rl(c2my, 40);
        asm volatile("" ::: "memory");
        __builtin_amdgcn_wave_barrier();
    }
}

extern "C" void kernel_launch(void* const* d_in, const int* in_sizes, int n_in,
                              void* d_out, int out_size, void* d_ws, size_t ws_size,
                              hipStream_t stream) {
    const float* x    = (const float*)d_in[0];
    const float* Wih1 = (const float*)d_in[1];
    const float* Whh1 = (const float*)d_in[2];
    const float* bih1 = (const float*)d_in[3];
    const float* bhh1 = (const float*)d_in[4];
    const float* Wih2 = (const float*)d_in[5];
    const float* Whh2 = (const float*)d_in[6];
    const float* bih2 = (const float*)d_in[7];
    const float* bhh2 = (const float*)d_in[8];
    float* out = (float*)d_out;

    const int B = 1024;
    const int T = in_sizes[0] / B;        // 4096 (multiple of 4)
    const int F = out_size / B - T;       // 16

    hipLaunchKernelGGL(lstm2_kernel, dim3(B), dim3(64), 0, stream,
                       x, Wih1, Whh1, bih1, bhh1, Wih2, Whh2, bih2, bhh2, out, T, F);
}